// Round 13
// baseline (41.475 us; speedup 1.0000x reference)
//
#include <hip/hip_runtime.h>

#define CF 2048
#define TT 64
#define TP 65
#define KK 16
#define SS 4
#define EE 64
#define BB 2
#define DT_CONST 0.005f

// ws float layout: [0, 34816) transposed gram partials: slot (b*136+p)*128 + tile
// [34816, +2048) wk fp32 [2][64][16]
#define WS_WK_F 34816

// ---------------- kernel A: sliding-correlation Gram, half-split lanes (R12 verbatim) ----
__global__ void __launch_bounds__(512, 1) kA_gram(const float* __restrict__ events,
                                                  float* __restrict__ ws) {
    __shared__ float xs[16][97];    // xpad: [0..7]=0, [8..71]=x, [72..96]=0
    __shared__ float S1L[16][16];
    __shared__ float part[16][136];
    const int tid = threadIdx.x;

    if (tid < 256) {
        const float4* src = reinterpret_cast<const float4*>(
            events + (size_t)blockIdx.x * 1024);
        float4 v = src[tid];
        int r = tid >> 4, c0 = ((tid & 15) << 2) + 8;
        xs[r][c0] = v.x; xs[r][c0+1] = v.y; xs[r][c0+2] = v.z; xs[r][c0+3] = v.w;
    }
    for (int idx = tid; idx < 16 * 33; idx += 512) {
        int rr = idx / 33, k = idx % 33;
        xs[rr][(k < 8) ? k : (k + 64)] = 0.f;
    }
    __syncthreads();

    const int r   = tid >> 5;
    const int c   = tid & 31;
    const int lag = c >> 1;
    const int h   = c & 1;
    const int off = h * 33;
    const float inv65 = 1.f / 65.f;

    {
        float s = 0.f;
#pragma unroll
        for (int j = 0; j < 32; ++j) s += xs[r][lag + off + j];
        if (!h) s += xs[r][lag + 32];
        s += __shfl_xor(s, 1, 64);
        if (!h) S1L[r][lag] = s;
    }
    __syncthreads();

    {
        float C = 0.f;
#pragma unroll
        for (int j = 0; j < 32; ++j) C += xs[r][off + j] * xs[r][off + j + lag];
        if (!h) C += xs[r][32] * xs[r][32 + lag];
        {
            float Ct = C + __shfl_xor(C, 1, 64);
            if (!h) part[r][lag] = Ct - S1L[r][0] * S1L[r][lag] * inv65;
        }
#pragma unroll
        for (int d1 = 1; d1 <= 15; ++d1) {
            const int add = d1 + off + 32 - h;
            const int rem = d1 - 1 + off;
            C += xs[r][add] * xs[r][add + lag] - xs[r][rem] * xs[r][rem + lag];
            if (lag + d1 <= 15) {
                float Ct = C + __shfl_xor(C, 1, 64);
                if (!h) {
                    int p = 16 * d1 - ((d1 * (d1 - 1)) >> 1) + lag;
                    part[r][p] = Ct - S1L[r][d1] * S1L[r][d1 + lag] * inv65;
                }
            }
        }
    }
    __syncthreads();

    if (tid < 136) {
        float g = 0.f;
#pragma unroll
        for (int rr = 0; rr < 16; ++rr) g += part[rr][tid];
        ws[((size_t)((blockIdx.x >> 7) * 136 + tid)) * 128 + (blockIdx.x & 127)] = g;
    }
}

// ---------------- kernel M: reduce partials, fv, MLP, softmax, wk (fp32) ----------------
__global__ void __launch_bounds__(256, 1) kM_mlp(const float* __restrict__ tc,
        const float* __restrict__ tk, const float* __restrict__ w1,
        const float* __restrict__ b1, const float* __restrict__ w2,
        const float* __restrict__ b2, float* __restrict__ ws) {
    __shared__ float Gf[2 * 256];
    __shared__ float combL[SS * EE * KK];
    __shared__ float fvL[BB * SS];
    __shared__ float attnL[BB][SS];
    const int tid = threadIdx.x;

    for (int v = tid; v < 272; v += 256) {
        int b = (v >= 136) ? 1 : 0;
        int p = v - b * 136;
        int pp = p, d1 = 0;
        while (pp >= KK - d1) { pp -= KK - d1; ++d1; }
        int d2 = d1 + pp;
        const float4* rp = reinterpret_cast<const float4*>(ws + (size_t)v * 128);
        float acc = 0.f;
#pragma unroll
        for (int i = 0; i < 32; ++i) { float4 q = rp[i]; acc += (q.x + q.y) + (q.z + q.w); }
        Gf[b * 256 + d1 * KK + d2] = acc;
        Gf[b * 256 + d2 * KK + d1] = acc;
    }
    {
        int s = tid >> 6;
        float inv = DT_CONST / tc[s];
        float dk[KK]; float dsum = 0.f;
#pragma unroll
        for (int j = 0; j < KK; ++j) { dk[j] = expf(-(float)j * inv); dsum += dk[j]; }
        float rn = 1.f / dsum;
#pragma unroll
        for (int i = 0; i < 4; ++i) {
            float4 v = reinterpret_cast<const float4*>(tk + tid * KK)[i];
            combL[tid * KK + 4*i + 0] = dk[4*i + 0] * rn * v.x;
            combL[tid * KK + 4*i + 1] = dk[4*i + 1] * rn * v.y;
            combL[tid * KK + 4*i + 2] = dk[4*i + 2] * rn * v.z;
            combL[tid * KK + 4*i + 3] = dk[4*i + 3] * rn * v.w;
        }
    }
    __syncthreads();
    {
        float cvec[KK];
#pragma unroll
        for (int i = 0; i < 4; ++i) {
            float4 v = reinterpret_cast<const float4*>(combL + tid * KK)[i];
            cvec[4*i] = v.x; cvec[4*i+1] = v.y; cvec[4*i+2] = v.z; cvec[4*i+3] = v.w;
        }
        float acc0 = 0.f, acc1 = 0.f;
#pragma unroll
        for (int d1 = 0; d1 < KK; ++d1) {
            float cd1 = cvec[d1];
            float t0 = 0.5f * Gf[d1 * KK + d1] * cd1;
            float t1 = 0.5f * Gf[256 + d1 * KK + d1] * cd1;
#pragma unroll
            for (int d2 = d1 + 1; d2 < KK; ++d2) {
                t0 += Gf[d1 * KK + d2] * cvec[d2];
                t1 += Gf[256 + d1 * KK + d2] * cvec[d2];
            }
            acc0 += 2.f * cd1 * t0;
            acc1 += 2.f * cd1 * t1;
        }
#pragma unroll
        for (int sft = 1; sft < 64; sft <<= 1) {
            acc0 += __shfl_xor(acc0, sft, 64);
            acc1 += __shfl_xor(acc1, sft, 64);
        }
        if ((tid & 63) == 0) {
            const float scale = 1.f / 8388608.f;   // 1/(E*(Tp-1)*Cf)
            fvL[(tid >> 6)]     = acc0 * scale;
            fvL[4 + (tid >> 6)] = acc1 * scale;
        }
    }
    __syncthreads();
    if (tid < 2) {
        int b = tid;
        float h[8];
#pragma unroll
        for (int i = 0; i < 8; ++i) {
            float a = b1[i];
#pragma unroll
            for (int s = 0; s < SS; ++s) a += fvL[b * SS + s] * w1[i * SS + s];
            h[i] = a > 0.f ? a : 0.f;
        }
        float lg[SS]; float mx = -1e30f;
#pragma unroll
        for (int s = 0; s < SS; ++s) {
            float a = b2[s];
#pragma unroll
            for (int i = 0; i < 8; ++i) a += h[i] * w2[s * 8 + i];
            lg[s] = a; mx = fmaxf(mx, a);
        }
        float se = 0.f;
#pragma unroll
        for (int s = 0; s < SS; ++s) { lg[s] = expf(lg[s] - mx); se += lg[s]; }
#pragma unroll
        for (int s = 0; s < SS; ++s) attnL[b][s] = lg[s] / se;
    }
    __syncthreads();
    {
#pragma unroll
        for (int j = 0; j < 8; ++j) {
            int o = tid * 8 + j;                    // [0,2048)
            int b = o >> 10, e = (o >> 4) & 63, k = o & 15;
            float a = 0.f;
#pragma unroll
            for (int s = 0; s < SS; ++s)
                a += attnL[b][s] * combL[(s * EE + e) * KK + k];
            ws[WS_WK_F + o] = a;
        }
    }
}

// ---------------- kernel C: conv, R4 seg geometry (measured-good), coalesced writes ----
// grid 4096 chunks of 64 rows; block 256 = 4 waves; wave=seg(16/17 t's), lane=row.
__global__ void __launch_bounds__(256, 4) kC_conv(const float* __restrict__ events,
                                                  const float* __restrict__ ws,
                                                  float* __restrict__ out) {
    __shared__ float buf[64 * TP];               // 16640 B
    const int tid = threadIdx.x;
    const int seg = tid >> 6;                    // wave-uniform
    const int r   = tid & 63;
    const int c   = blockIdx.x;                  // [0,4096)
    const int be  = c >> 5;
    const int rowg = (c << 6) + r;
    const int b   = be >> 6;
    const float* xr = events + (((size_t)b << 11) + (rowg & (CF - 1))) * TT;

    float wk[KK];
#pragma unroll
    for (int i = 0; i < 4; ++i) {
        float4 v = reinterpret_cast<const float4*>(ws + WS_WK_F + be * KK)[i];
        wk[4*i] = v.x; wk[4*i+1] = v.y; wk[4*i+2] = v.z; wk[4*i+3] = v.w;
    }

    float win[32];
    if (seg == 0) {                              // t 0..15, u -8..22
#pragma unroll
        for (int k = 0; k < 8; ++k) win[k] = 0.f;
#pragma unroll
        for (int k = 0; k < 6; ++k) {
            float4 v = reinterpret_cast<const float4*>(xr)[k];
            win[8+4*k] = v.x; win[9+4*k] = v.y; win[10+4*k] = v.z; win[11+4*k] = v.w;
        }
    } else if (seg == 3) {                       // t 48..64, u 40..71
#pragma unroll
        for (int k = 0; k < 6; ++k) {
            float4 v = reinterpret_cast<const float4*>(xr + 40)[k];
            win[4*k] = v.x; win[4*k+1] = v.y; win[4*k+2] = v.z; win[4*k+3] = v.w;
        }
#pragma unroll
        for (int k = 24; k < 32; ++k) win[k] = 0.f;
    } else {                                     // seg1: u 8..39, seg2: u 24..55
        const float* bp2 = xr + (seg == 1 ? 8 : 24);
#pragma unroll
        for (int k = 0; k < 8; ++k) {
            float4 v = reinterpret_cast<const float4*>(bp2)[k];
            win[4*k] = v.x; win[4*k+1] = v.y; win[4*k+2] = v.z; win[4*k+3] = v.w;
        }
    }

    float acc[16];
#pragma unroll
    for (int i = 0; i < 16; ++i) acc[i] = 0.f;
#pragma unroll
    for (int dt = 0; dt < 16; ++dt) {
        float w = wk[dt];
#pragma unroll
        for (int i = 0; i < 16; ++i) acc[i] += w * win[i + dt];
    }
    float acc16 = 0.f;
    if (seg == 3) {
#pragma unroll
        for (int dt = 0; dt < 8; ++dt) acc16 += wk[dt] * win[16 + dt];
    }

    float* bp = buf + r * TP + seg * 16;
#pragma unroll
    for (int i = 0; i < 16; ++i) bp[i] = acc[i];
    if (seg == 3) bp[16] = acc16;
    __syncthreads();

    const float4* bs = reinterpret_cast<const float4*>(buf);
    float4* od = reinterpret_cast<float4*>(out + (size_t)c * (64 * TP));
    for (int j = tid; j < 64 * TP / 4; j += 256)
        od[j] = bs[j];
}

extern "C" void kernel_launch(void* const* d_in, const int* in_sizes, int n_in,
                              void* d_out, int out_size, void* d_ws, size_t ws_size,
                              hipStream_t stream) {
    const float* events = (const float*)d_in[0];
    const float* tc     = (const float*)d_in[1];
    const float* tk     = (const float*)d_in[2];
    const float* w1     = (const float*)d_in[3];
    const float* b1     = (const float*)d_in[4];
    const float* w2     = (const float*)d_in[5];
    const float* b2     = (const float*)d_in[6];
    float* out = (float*)d_out;
    float* ws  = (float*)d_ws;

    hipLaunchKernelGGL(kA_gram, dim3(256),  dim3(512), 0, stream, events, ws);
    hipLaunchKernelGGL(kM_mlp,  dim3(1),    dim3(256), 0, stream, tc, tk, w1, b1, w2, b2, ws);
    hipLaunchKernelGGL(kC_conv, dim3(4096), dim3(256), 0, stream, events, ws, out);
}